// Round 1
// baseline (22744.275 us; speedup 1.0000x reference)
//
#include <hip/hip_runtime.h>

typedef __attribute__((ext_vector_type(8))) short bhalf8;
typedef __attribute__((ext_vector_type(4))) float floatx4;

#define NSLOTS 502
#define NWG 64
#define BLOCK 384

__device__ __forceinline__ unsigned short f2b(float f) {
  unsigned u = __float_as_uint(f);
  return (unsigned short)((u + 0x7FFFu + ((u >> 16) & 1u)) >> 16);
}

__global__ void prep_w(const float* __restrict__ wih, const float* __restrict__ whh,
                       const float* __restrict__ wout,
                       unsigned short* __restrict__ wihb, unsigned short* __restrict__ whhb,
                       unsigned short* __restrict__ woutb) {
  size_t i0 = (size_t)blockIdx.x * blockDim.x + threadIdx.x;
  size_t stride = (size_t)gridDim.x * blockDim.x;
  for (size_t i = i0; i < 6291456u; i += stride) { wihb[i] = f2b(wih[i]); whhb[i] = f2b(whh[i]); }
  for (size_t i = i0; i < 163840u; i += stride) woutb[i] = f2b(wout[i]);
}

// res_output (B=64, H=1024, T=500) f32  ->  xb (T, B, H) bf16
__global__ void prep_x(const float* __restrict__ x, unsigned short* __restrict__ xb) {
  __shared__ float tile[32][33];
  int b = blockIdx.z;
  int h0 = blockIdx.y * 32, t0 = blockIdx.x * 32;
  int tx = threadIdx.x, ty = threadIdx.y;
  #pragma unroll
  for (int i = 0; i < 32; i += 8) {
    int t = t0 + tx;
    if (t < 500) tile[ty + i][tx] = x[((size_t)b * 1024 + h0 + ty + i) * 500 + t];
  }
  __syncthreads();
  #pragma unroll
  for (int i = 0; i < 32; i += 8) {
    int t = t0 + ty + i;
    if (t < 500) xb[((size_t)t * 64 + b) * 1024 + h0 + tx] = f2b(tile[tx][ty + i]);
  }
}

// ws layout (bytes):
// 0        : barrier counters (512 int)
// 2048     : h0f[0]  (64*1024 f32)      264192 : h0f[1]
// 526336   : h1f[0]                      788480 : h1f[1]
// 1050624  : h0b[0] (64*1024 bf16)      1181696: h0b[1]
// 1312768  : h1b[0]                     1443840: h1b[1]
// --- zero region ends at 1574912 ---
// 1574912  : Woutb (160*1024 bf16)
// 1902592  : Wihb  (2*3072*1024 bf16)
// 14485504 : Whhb
// 27068416 : Xb    (500*64*1024 bf16)   -> total 92604416

__launch_bounds__(BLOCK, 1)
__global__ void gru_main(const unsigned short* __restrict__ xb,
                         const unsigned short* __restrict__ wihb,
                         const unsigned short* __restrict__ whhb,
                         const unsigned short* __restrict__ woutb,
                         const float* __restrict__ bih, const float* __restrict__ bhh,
                         const float* __restrict__ bout,
                         char* __restrict__ wsb, float* __restrict__ out) {
  int* cnt = (int*)wsb;
  float* h0f0 = (float*)(wsb + 2048);
  float* h0f1 = (float*)(wsb + 264192);
  float* h1f0 = (float*)(wsb + 526336);
  float* h1f1 = (float*)(wsb + 788480);
  unsigned short* h0b0 = (unsigned short*)(wsb + 1050624);
  unsigned short* h0b1 = (unsigned short*)(wsb + 1181696);
  unsigned short* h1b0 = (unsigned short*)(wsb + 1312768);
  unsigned short* h1b1 = (unsigned short*)(wsb + 1443840);

  const int wg = blockIdx.x;
  const int layer = wg >> 5;      // 0: computes h0(s); 1: computes h1(s-1)
  const int c = wg & 31;          // column-chunk: owns n in [c*32, c*32+32)
  const int n0 = c * 32;
  const int tid = threadIdx.x;
  const int w = tid >> 6;         // wave 0..5
  const int l = tid & 63;
  const int l15 = l & 15, l4 = l >> 4;
  const int sd = w / 3, g = w % 3;  // side (0=input,1=hidden), gate (r,z,n)

  __shared__ __align__(16) char smem[50688];  // As[2][64][128]bf16 (32KB) / Gs[6][64][33]f32 overlaid

  const unsigned short* Wside = (sd == 0) ? (wihb + (size_t)layer * 3145728)
                                          : (whhb + (size_t)layer * 3145728);
  const float* bi = bih + layer * 3072;
  const float* bh = bhh + layer * 3072;

  int dead = 0;

  for (int s = 0; s < NSLOTS; ++s) {
    const int p = s & 1;
    const bool activeL = (layer == 0) ? (s <= 499) : (s >= 1 && s <= 500);
    if (activeL) {
      const unsigned short *Agi, *Agh;
      const float* hpf;
      float* houtf; unsigned short* houtb;
      if (layer == 0) {
        Agi = xb + (size_t)s * 65536;          // x(s)
        Agh = p ? h0b0 : h0b1;                 // h0(s-1)
        hpf = p ? h0f0 : h0f1;
        houtf = p ? h0f1 : h0f0;               // h0(s) -> parity s&1
        houtb = p ? h0b1 : h0b0;
      } else {
        Agi = p ? h0b0 : h0b1;                 // h0(s-1)
        Agh = p ? h1b1 : h1b0;                 // h1(s-2)
        hpf = p ? h1f1 : h1f0;
        houtf = p ? h1f0 : h1f1;               // h1(s-1) -> parity (s-1)&1
        houtb = p ? h1b0 : h1b1;
      }
      floatx4 acc[4][2];
      #pragma unroll
      for (int m = 0; m < 4; ++m) {
        acc[m][0] = (floatx4){0.f, 0.f, 0.f, 0.f};
        acc[m][1] = (floatx4){0.f, 0.f, 0.f, 0.f};
      }
      const unsigned short* wrow0 = Wside + (size_t)(g * 1024 + n0 + l15) * 1024;
      const unsigned short* wrow1 = wrow0 + (size_t)16 * 1024;

      for (int kc = 0; kc < 8; ++kc) {
        // stage A chunk (both sides, 64 rows x 128 k) into LDS, XOR bank-swizzled
        for (int q = tid; q < 2048; q += BLOCK) {
          int side = q >> 10, rem = q & 1023, row = rem >> 4, g16 = rem & 15;
          const unsigned short* src = (side ? Agh : Agi) + (size_t)row * 1024 + kc * 128 + g16 * 8;
          int dstb = (side << 14) + row * 256 + ((g16 * 16) ^ ((row & 7) << 4));
          *(bhalf8*)(smem + dstb) = *(const bhalf8*)src;
        }
        __syncthreads();
        const char* Abase = smem + (sd << 14);
        #pragma unroll
        for (int kl = 0; kl < 4; ++kl) {
          int kg = kc * 128 + kl * 32 + l4 * 8;
          bhalf8 b0 = *(const bhalf8*)(wrow0 + kg);
          bhalf8 b1 = *(const bhalf8*)(wrow1 + kg);
          #pragma unroll
          for (int m = 0; m < 4; ++m) {
            int row = m * 16 + l15;
            bhalf8 a = *(const bhalf8*)(Abase + row * 256 + ((kl * 64 + l4 * 16) ^ ((row & 7) << 4)));
            acc[m][0] = __builtin_amdgcn_mfma_f32_16x16x32_bf16(a, b0, acc[m][0], 0, 0, 0);
            acc[m][1] = __builtin_amdgcn_mfma_f32_16x16x32_bf16(a, b1, acc[m][1], 0, 0, 0);
          }
        }
        __syncthreads();
      }
      // dump accumulators to LDS gate planes: Gs[side*3+g][b][j]
      float* Gsf = (float*)smem;
      int plane = (sd * 3 + g) * 2112;
      #pragma unroll
      for (int m = 0; m < 4; ++m)
        #pragma unroll
        for (int u = 0; u < 2; ++u)
          #pragma unroll
          for (int i = 0; i < 4; ++i)
            Gsf[plane + (m * 16 + l4 * 4 + i) * 33 + u * 16 + l15] = acc[m][u][i];
      __syncthreads();
      // gate math epilogue (fp32)
      for (int e = tid; e < 2048; e += BLOCK) {
        int b = e >> 5, j = e & 31, n = n0 + j;
        float ir  = Gsf[0 * 2112 + b * 33 + j] + bi[n];
        float iz  = Gsf[1 * 2112 + b * 33 + j] + bi[1024 + n];
        float inn = Gsf[2 * 2112 + b * 33 + j] + bi[2048 + n];
        float hr  = Gsf[3 * 2112 + b * 33 + j] + bh[n];
        float hz  = Gsf[4 * 2112 + b * 33 + j] + bh[1024 + n];
        float hn  = Gsf[5 * 2112 + b * 33 + j] + bh[2048 + n];
        float r = 1.f / (1.f + expf(-(ir + hr)));
        float z = 1.f / (1.f + expf(-(iz + hz)));
        float nc = tanhf(inn + r * hn);
        float hp = hpf[(size_t)b * 1024 + n];
        float hnew = (1.f - z) * nc + z * hp;
        float hzo = 0.1f * hp + 0.9f * hnew;   // eval-mode zoneout
        houtf[(size_t)b * 1024 + n] = hzo;
        houtb[(size_t)b * 1024 + n] = f2b(hzo);
      }
    }
    // y(s-2) = h1(s-2) @ Wout^T + bout, folded into layer-0 WGs c<10, waves 0-3
    if (layer == 0 && c < 10 && s >= 2 && w < 4) {
      const unsigned short* Ay = p ? h1b1 : h1b0;   // h1(s-2)
      const unsigned short* arow = Ay + (size_t)(w * 16 + l15) * 1024;
      const unsigned short* brow = woutb + (size_t)(c * 16 + l15) * 1024;
      floatx4 accy = (floatx4){0.f, 0.f, 0.f, 0.f};
      #pragma unroll
      for (int ks = 0; ks < 32; ++ks) {
        int kg = ks * 32 + l4 * 8;
        bhalf8 a = *(const bhalf8*)(arow + kg);
        bhalf8 bb = *(const bhalf8*)(brow + kg);
        accy = __builtin_amdgcn_mfma_f32_16x16x32_bf16(a, bb, accy, 0, 0, 0);
      }
      int col = c * 16 + l15;
      float bo = bout[col];
      int t2 = s - 2;
      #pragma unroll
      for (int i = 0; i < 4; ++i) {
        int b = w * 16 + l4 * 4 + i;
        out[(size_t)b * 80000 + (size_t)(col >> 1) * 1000 + t2 * 2 + (col & 1)] = accy[i] + bo;
      }
    }
    // device-wide barrier (one counter per slot, pre-zeroed; no reset race)
    if (s < NSLOTS - 1) {
      __syncthreads();
      if (tid == 0) {
        __threadfence();
        atomicAdd(&cnt[s], 1);
        if (!dead) {
          int it = 0;
          while (__hip_atomic_load(&cnt[s], __ATOMIC_RELAXED, __HIP_MEMORY_SCOPE_AGENT) < NWG) {
            __builtin_amdgcn_s_sleep(2);
            if (++it > 3000000) { dead = 1; break; }  // failsafe: no hang
          }
        }
        __threadfence();
      }
      __syncthreads();
    }
  }
}

extern "C" void kernel_launch(void* const* d_in, const int* in_sizes, int n_in,
                              void* d_out, int out_size, void* d_ws, size_t ws_size,
                              hipStream_t stream) {
  const float* res  = (const float*)d_in[0];
  const float* Wih  = (const float*)d_in[1];
  const float* Whh  = (const float*)d_in[2];
  const float* bih  = (const float*)d_in[3];
  const float* bhh  = (const float*)d_in[4];
  const float* Wout = (const float*)d_in[5];
  const float* bout = (const float*)d_in[6];
  float* out = (float*)d_out;
  char* ws = (char*)d_ws;
  if (ws_size < 92604416u) return;  // workspace too small; fail loudly via wrong output

  unsigned short* woutb = (unsigned short*)(ws + 1574912);
  unsigned short* wihb  = (unsigned short*)(ws + 1902592);
  unsigned short* whhb  = (unsigned short*)(ws + 14485504);
  unsigned short* xb    = (unsigned short*)(ws + 27068416);

  // zero barrier counters + h state (fp32 and bf16, both parities)
  hipMemsetAsync(ws, 0, 1574912, stream);
  prep_w<<<4096, 256, 0, stream>>>(Wih, Whh, Wout, wihb, whhb, woutb);
  prep_x<<<dim3(16, 32, 64), dim3(32, 8), 0, stream>>>(res, xb);
  gru_main<<<NWG, BLOCK, 0, stream>>>(xb, wihb, whhb, woutb, bih, bhh, bout, ws, out);
}

// Round 3
// 21003.790 us; speedup vs baseline: 1.0829x; 1.0829x over previous
//
#include <hip/hip_runtime.h>

typedef __attribute__((ext_vector_type(8))) short bhalf8;
typedef __attribute__((ext_vector_type(4))) float floatx4;

#define NSLOTS 502
#define NWG 64
#define BLOCK 384

__device__ __forceinline__ unsigned short f2b(float f) {
  unsigned u = __float_as_uint(f);
  return (unsigned short)((u + 0x7FFFu + ((u >> 16) & 1u)) >> 16);
}

// Coherent (cross-XCD) 8B load/store: relaxed agent-scope atomics compile to
// global_load/store_dwordx2 with sc0 sc1 -> bypass non-coherent per-XCD L2,
// served by the coherent MALL. No buffer_wbl2/buffer_inv cache wiping
// (round-1's 45us/slot + weight eviction came from __threadfence()).
__device__ __forceinline__ unsigned long long cload(const unsigned long long* p) {
  return __hip_atomic_load(p, __ATOMIC_RELAXED, __HIP_MEMORY_SCOPE_AGENT);
}
__device__ __forceinline__ void cstore(unsigned long long* p, unsigned long long v) {
  __hip_atomic_store(p, v, __ATOMIC_RELAXED, __HIP_MEMORY_SCOPE_AGENT);
}

__global__ void prep_w(const float* __restrict__ wih, const float* __restrict__ whh,
                       const float* __restrict__ wout,
                       unsigned short* __restrict__ wihb, unsigned short* __restrict__ whhb,
                       unsigned short* __restrict__ woutb) {
  size_t i0 = (size_t)blockIdx.x * blockDim.x + threadIdx.x;
  size_t stride = (size_t)gridDim.x * blockDim.x;
  for (size_t i = i0; i < 6291456u; i += stride) { wihb[i] = f2b(wih[i]); whhb[i] = f2b(whh[i]); }
  for (size_t i = i0; i < 163840u; i += stride) woutb[i] = f2b(wout[i]);
}

// res_output (B=64, H=1024, T=500) f32  ->  xb (T, B, H) bf16
__global__ void prep_x(const float* __restrict__ x, unsigned short* __restrict__ xb) {
  __shared__ float tile[32][33];
  int b = blockIdx.z;
  int h0 = blockIdx.y * 32, t0 = blockIdx.x * 32;
  int tx = threadIdx.x, ty = threadIdx.y;
  #pragma unroll
  for (int i = 0; i < 32; i += 8) {
    int t = t0 + tx;
    if (t < 500) tile[ty + i][tx] = x[((size_t)b * 1024 + h0 + ty + i) * 500 + t];
  }
  __syncthreads();
  #pragma unroll
  for (int i = 0; i < 32; i += 8) {
    int t = t0 + ty + i;
    if (t < 500) xb[((size_t)t * 64 + b) * 1024 + h0 + tx] = f2b(tile[tx][ty + i]);
  }
}

// ws layout (bytes):
// 0        : barrier counters (512 int)
// 2048     : h0b[0] (64*1024 bf16 = 128KB)   133120 : h0b[1]
// 264192   : h1b[0]                          395264 : h1b[1]
// --- zero region ends at 526336 ---
// 526336   : Woutb (160*1024 bf16)
// 854016   : Wihb  (2*3072*1024 bf16)
// 13436928 : Whhb
// 26019840 : Xb (500*64*1024 bf16)  -> total 91555840

__launch_bounds__(BLOCK, 1)
__global__ void gru_main(const unsigned short* __restrict__ xb,
                         const unsigned short* __restrict__ wihb,
                         const unsigned short* __restrict__ whhb,
                         const unsigned short* __restrict__ woutb,
                         const float* __restrict__ bih, const float* __restrict__ bhh,
                         const float* __restrict__ bout,
                         char* __restrict__ wsb, float* __restrict__ out) {
  int* cnt = (int*)wsb;
  unsigned short* h0b0 = (unsigned short*)(wsb + 2048);
  unsigned short* h0b1 = (unsigned short*)(wsb + 133120);
  unsigned short* h1b0 = (unsigned short*)(wsb + 264192);
  unsigned short* h1b1 = (unsigned short*)(wsb + 395264);

  const int wg = blockIdx.x;
  const int layer = wg >> 5;      // 0: computes h0(s); 1: computes h1(s-1)
  const int c = wg & 31;          // column-chunk: owns n in [c*32, c*32+32)
  const int n0 = c * 32;
  const int tid = threadIdx.x;
  const int w = tid >> 6;         // wave 0..5
  const int l = tid & 63;
  const int l15 = l & 15, l4 = l >> 4;
  const int sd = w / 3, g = w % 3;  // side (0=input,1=hidden), gate (r,z,n)

  // LDS: [0,32K) A buf0, [32K,64K) A buf1 (each: side0 16K + side1 16K, XOR-swizzled).
  // Gsf gate planes (50688B) overlay the A bufs after the k-loop.
  __shared__ __align__(16) char smem[65536];

  const unsigned short* Wside = (sd == 0) ? (wihb + (size_t)layer * 3145728)
                                          : (whhb + (size_t)layer * 3145728);
  const float* bi = bih + layer * 3072;
  const float* bh = bhh + layer * 3072;
  const unsigned short* wrow0 = Wside + (size_t)(g * 1024 + n0 + l15) * 1024;
  const unsigned short* wrow1 = wrow0 + (size_t)16 * 1024;

  // fp32 zoneout carry in REGISTERS: thread handles the same (b,j) pairs every
  // step (static uu = tid + r*BLOCK mapping), so no LDS round-trip needed.
  float hcr[2][4] = {{0.f, 0.f, 0.f, 0.f}, {0.f, 0.f, 0.f, 0.f}};

  int dead = 0;

  for (int s = 0; s < NSLOTS; ++s) {
    const int p = s & 1;
    const bool activeL = (layer == 0) ? (s <= 499) : (s >= 1 && s <= 500);
    if (activeL) {
      const unsigned long long* src0;
      const unsigned long long* src1;
      unsigned short* houtb;
      if (layer == 0) {
        src0 = (const unsigned long long*)(xb + (size_t)s * 65536);  // x(s): plain cacheable
        src1 = (const unsigned long long*)(p ? h0b0 : h0b1);         // h0(s-1): coherent
        houtb = p ? h0b1 : h0b0;                                     // h0(s)
      } else {
        src0 = (const unsigned long long*)(p ? h0b0 : h0b1);         // h0(s-1): coherent
        src1 = (const unsigned long long*)(p ? h1b1 : h1b0);         // h1(s-2): coherent
        houtb = p ? h1b0 : h1b1;                                     // h1(s-1)
      }
      const bool s0coh = (layer != 0);  // x side is read-only -> let L2 cache it

      auto stage_load = [&](int kc, unsigned long long* lv) {
        #pragma unroll
        for (int i = 0; i < 11; ++i) {
          int idx = tid + i * BLOCK;
          if (idx < 4096) {
            int side = idx >> 11, rem = idx & 2047;
            int row = rem >> 5, u8 = rem & 31;
            size_t off = (size_t)row * 256 + kc * 32 + u8;
            lv[i] = side ? cload(src1 + off) : (s0coh ? cload(src0 + off) : src0[off]);
          }
        }
      };
      auto stage_write = [&](int kc, const unsigned long long* lv) {
        char* bufb = smem + ((kc & 1) << 15);
        #pragma unroll
        for (int i = 0; i < 11; ++i) {
          int idx = tid + i * BLOCK;
          if (idx < 4096) {
            int side = idx >> 11, rem = idx & 2047;
            int row = rem >> 5, u8 = rem & 31;
            int dstb = (side << 14) + row * 256 + (((u8 >> 1) << 4) ^ ((row & 7) << 4)) + ((u8 & 1) << 3);
            *(unsigned long long*)(bufb + dstb) = lv[i];
          }
        }
      };

      floatx4 acc[4][2];
      #pragma unroll
      for (int m = 0; m < 4; ++m) {
        acc[m][0] = (floatx4){0.f, 0.f, 0.f, 0.f};
        acc[m][1] = (floatx4){0.f, 0.f, 0.f, 0.f};
      }

      auto compute_kc = [&](int kc) {
        const char* Abase = smem + ((kc & 1) << 15) + (sd << 14);
        #pragma unroll
        for (int kl = 0; kl < 4; ++kl) {
          int kg = kc * 128 + kl * 32 + l4 * 8;
          bhalf8 b0 = *(const bhalf8*)(wrow0 + kg);   // plain: weights stay L2-resident
          bhalf8 b1 = *(const bhalf8*)(wrow1 + kg);
          #pragma unroll
          for (int m = 0; m < 4; ++m) {
            int row = m * 16 + l15;
            bhalf8 a = *(const bhalf8*)(Abase + row * 256 + ((kl * 64 + l4 * 16) ^ ((row & 7) << 4)));
            acc[m][0] = __builtin_amdgcn_mfma_f32_16x16x32_bf16(a, b0, acc[m][0], 0, 0, 0);
            acc[m][1] = __builtin_amdgcn_mfma_f32_16x16x32_bf16(a, b1, acc[m][1], 0, 0, 0);
          }
        }
      };

      unsigned long long lv[11];
      stage_load(0, lv);
      stage_write(0, lv);
      __syncthreads();
      for (int kc = 0; kc < 8; ++kc) {
        unsigned long long nv[11];
        if (kc < 7) stage_load(kc + 1, nv);   // issue loads early: latency hides under MFMAs
        compute_kc(kc);
        if (kc < 7) stage_write(kc + 1, nv);  // waits + LDS writes after compute
        __syncthreads();
      }

      // dump accumulators to LDS gate planes: Gs[side*3+g][b][j] (overlays A bufs)
      float* Gsf = (float*)smem;
      int plane = (sd * 3 + g) * 2112;
      #pragma unroll
      for (int m = 0; m < 4; ++m)
        #pragma unroll
        for (int u = 0; u < 2; ++u)
          #pragma unroll
          for (int i = 0; i < 4; ++i)
            Gsf[plane + (m * 16 + l4 * 4 + i) * 33 + u * 16 + l15] = acc[m][u][i];
      __syncthreads();

      // gate math epilogue (fp32); zoneout carry lives in registers
      #pragma unroll
      for (int r = 0; r < 2; ++r) {
        int uu = tid + r * BLOCK;
        if (uu < 512) {
          int b = uu >> 3, j0 = (uu & 7) << 2;
          union { unsigned long long ull; unsigned short us[4]; } pk;
          #pragma unroll
          for (int q = 0; q < 4; ++q) {
            int j = j0 + q, n = n0 + j;
            float ir  = Gsf[0 * 2112 + b * 33 + j] + bi[n];
            float iz  = Gsf[1 * 2112 + b * 33 + j] + bi[1024 + n];
            float inn = Gsf[2 * 2112 + b * 33 + j] + bi[2048 + n];
            float hr  = Gsf[3 * 2112 + b * 33 + j] + bh[n];
            float hz  = Gsf[4 * 2112 + b * 33 + j] + bh[1024 + n];
            float hn  = Gsf[5 * 2112 + b * 33 + j] + bh[2048 + n];
            float rr = 1.f / (1.f + expf(-(ir + hr)));
            float z  = 1.f / (1.f + expf(-(iz + hz)));
            float nc = tanhf(inn + rr * hn);
            float hp = hcr[r][q];
            float hnew = (1.f - z) * nc + z * hp;
            float hzo = 0.1f * hp + 0.9f * hnew;   // eval-mode zoneout
            hcr[r][q] = hzo;
            pk.us[q] = f2b(hzo);
          }
          cstore((unsigned long long*)(houtb + (size_t)b * 1024 + n0 + j0), pk.ull);
        }
      }
    }

    // y(s-2) = h1(s-2) @ Wout^T + bout, folded into layer-0 WGs c<10, waves 0-3
    if (layer == 0 && c < 10 && s >= 2 && w < 4) {
      const unsigned short* Ay = p ? h1b1 : h1b0;   // h1(s-2)
      const unsigned long long* arow = (const unsigned long long*)(Ay + (size_t)(w * 16 + l15) * 1024);
      const unsigned short* brow = woutb + (size_t)(c * 16 + l15) * 1024;
      floatx4 accy = (floatx4){0.f, 0.f, 0.f, 0.f};
      #pragma unroll
      for (int ks = 0; ks < 32; ++ks) {
        int kg = ks * 32 + l4 * 8;
        union { unsigned long long u[2]; bhalf8 v; } av;
        av.u[0] = cload(arow + (kg >> 2));
        av.u[1] = cload(arow + (kg >> 2) + 1);
        bhalf8 bb = *(const bhalf8*)(brow + kg);
        accy = __builtin_amdgcn_mfma_f32_16x16x32_bf16(av.v, bb, accy, 0, 0, 0);
      }
      int col = c * 16 + l15;
      float bo = bout[col];
      int t2 = s - 2;
      #pragma unroll
      for (int i = 0; i < 4; ++i) {
        int b = w * 16 + l4 * 4 + i;
        out[(size_t)b * 80000 + (size_t)(col >> 1) * 1000 + t2 * 2 + (col & 1)] = accy[i] + bo;
      }
    }

    // device-wide barrier: relaxed agent atomics only — NO threadfence (no L2 wipe).
    // __syncthreads() before the add drains each wave's vmcnt, so all coherent
    // h-stores are globally visible (MALL) before the counter increments.
    if (s < NSLOTS - 1) {
      __syncthreads();
      if (tid == 0) {
        __hip_atomic_fetch_add(&cnt[s], 1, __ATOMIC_RELAXED, __HIP_MEMORY_SCOPE_AGENT);
        if (!dead) {
          int it = 0;
          while (__hip_atomic_load(&cnt[s], __ATOMIC_RELAXED, __HIP_MEMORY_SCOPE_AGENT) < NWG) {
            __builtin_amdgcn_s_sleep(1);
            if (++it > 2000000) { dead = 1; break; }  // failsafe: bounded, no hang
          }
        }
      }
      __syncthreads();
    }
  }
}

extern "C" void kernel_launch(void* const* d_in, const int* in_sizes, int n_in,
                              void* d_out, int out_size, void* d_ws, size_t ws_size,
                              hipStream_t stream) {
  const float* res  = (const float*)d_in[0];
  const float* Wih  = (const float*)d_in[1];
  const float* Whh  = (const float*)d_in[2];
  const float* bih  = (const float*)d_in[3];
  const float* bhh  = (const float*)d_in[4];
  const float* Wout = (const float*)d_in[5];
  const float* bout = (const float*)d_in[6];
  float* out = (float*)d_out;
  char* ws = (char*)d_ws;
  if (ws_size < 91555840u) return;  // workspace too small; fail loudly via wrong output

  unsigned short* woutb = (unsigned short*)(ws + 526336);
  unsigned short* wihb  = (unsigned short*)(ws + 854016);
  unsigned short* whhb  = (unsigned short*)(ws + 13436928);
  unsigned short* xb    = (unsigned short*)(ws + 26019840);

  // zero barrier counters + bf16 h state (both parities)
  hipMemsetAsync(ws, 0, 526336, stream);
  prep_w<<<4096, 256, 0, stream>>>(Wih, Whh, Wout, wihb, whhb, woutb);
  prep_x<<<dim3(16, 32, 64), dim3(32, 8), 0, stream>>>(res, xb);
  gru_main<<<NWG, BLOCK, 0, stream>>>(xb, wihb, whhb, woutb, bih, bhh, bout, ws, out);
}

// Round 4
// 14072.340 us; speedup vs baseline: 1.6162x; 1.4926x over previous
//
#include <hip/hip_runtime.h>

typedef __attribute__((ext_vector_type(8))) short bhalf8;
typedef __attribute__((ext_vector_type(4))) float floatx4;

#define NSLOTS 502
#define NWG 64
#define BLOCK 768   // 12 waves: (side 2) x (gate 3) x (col-half 2)

#define AS1 __attribute__((address_space(1)))
#define AS3 __attribute__((address_space(3)))
// global->LDS direct load, 16B/lane. aux=17 = sc0|sc1 (coherent: bypass L1/L2,
// served at MALL -> fresh cross-XCD data). aux=0 = normal cached (x side).
#define GLL_COH(g, s)   __builtin_amdgcn_global_load_lds((const AS1 unsigned*)(g), (AS3 unsigned*)(s), 16, 0, 17)
#define GLL_PLAIN(g, s) __builtin_amdgcn_global_load_lds((const AS1 unsigned*)(g), (AS3 unsigned*)(s), 16, 0, 0)

__device__ __forceinline__ unsigned short f2b(float f) {
  unsigned u = __float_as_uint(f);
  return (unsigned short)((u + 0x7FFFu + ((u >> 16) & 1u)) >> 16);
}

__device__ __forceinline__ unsigned long long cload(const unsigned long long* p) {
  return __hip_atomic_load(p, __ATOMIC_RELAXED, __HIP_MEMORY_SCOPE_AGENT);
}
__device__ __forceinline__ void cstore(unsigned long long* p, unsigned long long v) {
  __hip_atomic_store(p, v, __ATOMIC_RELAXED, __HIP_MEMORY_SCOPE_AGENT);
}

__global__ void prep_w(const float* __restrict__ wih, const float* __restrict__ whh,
                       const float* __restrict__ wout,
                       unsigned short* __restrict__ wihb, unsigned short* __restrict__ whhb,
                       unsigned short* __restrict__ woutb) {
  size_t i0 = (size_t)blockIdx.x * blockDim.x + threadIdx.x;
  size_t stride = (size_t)gridDim.x * blockDim.x;
  for (size_t i = i0; i < 6291456u; i += stride) { wihb[i] = f2b(wih[i]); whhb[i] = f2b(whh[i]); }
  for (size_t i = i0; i < 163840u; i += stride) woutb[i] = f2b(wout[i]);
}

// res_output (B=64, H=1024, T=500) f32  ->  xb (T, B, H) bf16
__global__ void prep_x(const float* __restrict__ x, unsigned short* __restrict__ xb) {
  __shared__ float tile[32][33];
  int b = blockIdx.z;
  int h0 = blockIdx.y * 32, t0 = blockIdx.x * 32;
  int tx = threadIdx.x, ty = threadIdx.y;
  #pragma unroll
  for (int i = 0; i < 32; i += 8) {
    int t = t0 + tx;
    if (t < 500) tile[ty + i][tx] = x[((size_t)b * 1024 + h0 + ty + i) * 500 + t];
  }
  __syncthreads();
  #pragma unroll
  for (int i = 0; i < 32; i += 8) {
    int t = t0 + ty + i;
    if (t < 500) xb[((size_t)t * 64 + b) * 1024 + h0 + tx] = f2b(tile[tx][ty + i]);
  }
}

// ws layout (bytes):
// 0       : arrival counters (512 int)
// 2048    : release flags    (512 int)
// 4096    : h0b[0] (64*1024 bf16 = 128KB)   135168 : h0b[1]
// 266240  : h1b[0]                          397312 : h1b[1]
// --- zero region ends at 528384 ---
// 528384  : Woutb (160*1024 bf16)
// 856064  : Wihb  (2*3072*1024 bf16)
// 13438976: Whhb
// 26021888: Xb (500*64*1024 bf16)  -> total 91557888

__launch_bounds__(BLOCK, 1)
__global__ void gru_main(const unsigned short* __restrict__ xb,
                         const unsigned short* __restrict__ wihb,
                         const unsigned short* __restrict__ whhb,
                         const unsigned short* __restrict__ woutb,
                         const float* __restrict__ bih, const float* __restrict__ bhh,
                         const float* __restrict__ bout,
                         char* __restrict__ wsb, float* __restrict__ out) {
  int* cnt = (int*)wsb;
  int* rel = (int*)(wsb + 2048);
  char* h0b[2] = { wsb + 4096, wsb + 135168 };
  char* h1b[2] = { wsb + 266240, wsb + 397312 };

  const int wg = blockIdx.x;
  const int layer = wg >> 5;       // 0: computes h0(s); 1: computes h1(s-1)
  const int c = wg & 31;           // column-chunk: n in [c*32, c*32+32)
  const int n0 = c * 32;
  const int tid = threadIdx.x;
  const int w = tid >> 6;          // wave 0..11
  const int l = tid & 63;
  const int l15 = l & 15, l4 = l >> 4;
  const int sd = w / 6;            // compute role: side 0=input,1=hidden
  const int rr6 = w % 6;
  const int g = rr6 >> 1;          // gate r,z,n
  const int u = rr6 & 1;           // col half (16 cols each)

  // LDS: 4-buffer ring of A chunks, each 32KB = [side(2)][row(64)][k(128)] bf16,
  // linear layout (global_load_lds) with XOR swizzle applied to the SOURCE addr.
  // Gate planes Gs (52KB f32) overlay bufs 0-1 after the k-loop.
  __shared__ __align__(16) char smem[131072];

  // ---- weights: VGPR-resident for the whole kernel (zero per-slot weight traffic)
  const unsigned short* Wside = (sd == 0 ? wihb : whhb) + (size_t)layer * 3145728;
  const unsigned short* wbase = Wside + (size_t)(g * 1024 + n0 + u * 16 + l15) * 1024 + l4 * 8;
  bhalf8 wreg[32];
  #pragma unroll
  for (int kl = 0; kl < 32; ++kl) wreg[kl] = *(const bhalf8*)(wbase + kl * 32);

  // ---- bias registers (static per-thread epilogue mapping: tid<512 -> (b, j0))
  const float* bi = bih + layer * 3072;
  const float* bh = bhh + layer * 3072;
  float bir[3][4], bhr[3][4];
  {
    int j0 = (tid & 7) << 2;
    #pragma unroll
    for (int q = 0; q < 4; ++q) {
      int n = n0 + j0 + q;
      #pragma unroll
      for (int gg = 0; gg < 3; ++gg) { bir[gg][q] = bi[gg * 1024 + n]; bhr[gg][q] = bh[gg * 1024 + n]; }
    }
  }
  float hcr[4] = {0.f, 0.f, 0.f, 0.f};  // fp32 zoneout carry (register-resident)

  int dead = 0;

  for (int s = 0; s < NSLOTS; ++s) {
    const int p = s & 1;
    const bool activeL = (layer == 0) ? (s <= 499) : (s >= 1 && s <= 500);

    if (activeL) {
      const char* src0;  // side 0 (input to this layer)
      const char* src1;  // side 1 (recurrent h)
      char* houtb;
      if (layer == 0) {
        src0 = (const char*)xb + (size_t)s * 131072;   // x(s): plain cached
        src1 = h0b[p ^ 1];                             // h0(s-1): coherent
        houtb = h0b[p];                                // h0(s)
      } else {
        src0 = h0b[p ^ 1];                             // h0(s-1): coherent
        src1 = h1b[p];                                 // h1(s-2): coherent
        houtb = h1b[p ^ 1];                            // h1(s-1)
      }
      const bool s0plain = (layer == 0);

      // waves 0-7 issue staging: wave w covers side (w>>2), 4 instrs of 1KB each.
      // LDS is linear; the bank-swizzle XOR is applied to the GLOBAL src address
      // (involution), so swizzled ds_reads below see the right data.
      auto issue_chunk = [&](int kc) {
        if (w < 8) {
          const char* sb = (w < 4) ? src0 : src1;
          char* bufb = smem + ((kc & 3) << 15) + ((w >> 2) << 14);
          #pragma unroll
          for (int i = 0; i < 4; ++i) {
            int q = ((w & 3) << 2) + i;            // 0..15 within side
            int row = (q << 2) + l4;               // q*4 + lane>>4
            int colb = l15 << 4;                   // (lane&15)*16
            const char* ga = sb + row * 2048 + kc * 256 + (colb ^ ((row & 7) << 4));
            char* la = bufb + (q << 10);
            if (s0plain && w < 4) GLL_PLAIN(ga, la); else GLL_COH(ga, la);
          }
        }
      };

      floatx4 acc[4];
      #pragma unroll
      for (int m = 0; m < 4; ++m) acc[m] = (floatx4){0.f, 0.f, 0.f, 0.f};

      issue_chunk(0); issue_chunk(1); issue_chunk(2);   // 3-deep prologue

      #pragma unroll
      for (int kc = 0; kc < 8; ++kc) {
        // counted waits: allow the 2 younger chunks (4 instr/wave each) to fly
        if (kc <= 5)      asm volatile("s_waitcnt vmcnt(8)" ::: "memory");
        else if (kc == 6) asm volatile("s_waitcnt vmcnt(4)" ::: "memory");
        else              asm volatile("s_waitcnt vmcnt(0)" ::: "memory");
        __builtin_amdgcn_s_barrier();
        __builtin_amdgcn_sched_barrier(0);
        const char* Ab = smem + ((kc & 3) << 15) + (sd << 14);
        #pragma unroll
        for (int klL = 0; klL < 4; ++klL) {
          #pragma unroll
          for (int m = 0; m < 4; ++m) {
            int row = m * 16 + l15;
            bhalf8 a = *(const bhalf8*)(Ab + row * 256 + ((klL * 64 + l4 * 16) ^ ((row & 7) << 4)));
            acc[m] = __builtin_amdgcn_mfma_f32_16x16x32_bf16(a, wreg[kc * 4 + klL], acc[m], 0, 0, 0);
          }
        }
        if (kc < 5) issue_chunk(kc + 3);
        __builtin_amdgcn_sched_barrier(0);
      }
      __syncthreads();   // all chunk reads done; safe to overlay Gs on bufs 0-1

      // gate planes Gs[side*3+g][b 64][col 32] (pad 34), col = u*16+l15
      float* Gsf = (float*)smem;
      int pl = (sd * 3 + g) * 2176;
      #pragma unroll
      for (int m = 0; m < 4; ++m)
        #pragma unroll
        for (int i = 0; i < 4; ++i)
          Gsf[pl + (m * 16 + l4 * 4 + i) * 34 + u * 16 + l15] = acc[m][i];
      __syncthreads();

      // epilogue: tid<512 handles (b = tid>>3, j0 = (tid&7)*4)
      if (tid < 512) {
        int b = tid >> 3, j0 = (tid & 7) << 2;
        union { unsigned long long ull; unsigned short us[4]; } pk;
        #pragma unroll
        for (int q = 0; q < 4; ++q) {
          int j = j0 + q;
          float ir  = Gsf[0 * 2176 + b * 34 + j] + bir[0][q];
          float iz  = Gsf[1 * 2176 + b * 34 + j] + bir[1][q];
          float inn = Gsf[2 * 2176 + b * 34 + j] + bir[2][q];
          float hr  = Gsf[3 * 2176 + b * 34 + j] + bhr[0][q];
          float hz  = Gsf[4 * 2176 + b * 34 + j] + bhr[1][q];
          float hn  = Gsf[5 * 2176 + b * 34 + j] + bhr[2][q];
          float rg = 1.f / (1.f + expf(-(ir + hr)));
          float zg = 1.f / (1.f + expf(-(iz + hz)));
          float nc = tanhf(inn + rg * hn);
          float hp = hcr[q];
          float hnew = (1.f - zg) * nc + zg * hp;
          float hzo = 0.1f * hp + 0.9f * hnew;   // eval-mode zoneout
          hcr[q] = hzo;
          pk.us[q] = f2b(hzo);
        }
        cstore((unsigned long long*)(houtb + (size_t)b * 2048 + ((n0 + j0) << 1)), pk.ull);
      }
    }

    if (s < NSLOTS - 1) {
      __syncthreads();   // drains all coherent h-stores (vmcnt 0) before arrival
      if (tid == 0) {
        int old = __hip_atomic_fetch_add(&cnt[s], 1, __ATOMIC_RELAXED, __HIP_MEMORY_SCOPE_AGENT);
        if (old == NWG - 1)
          __hip_atomic_store(&rel[s], 1, __ATOMIC_RELAXED, __HIP_MEMORY_SCOPE_AGENT);
      }
      // y(s-2) = h1(s-2) @ Wout^T + bout — no one depends on it, so it runs in
      // the barrier-slack window (after arrival, before release-wait).
      if (layer == 0 && c < 20 && s >= 2 && w < 2) {
        int tau = c * 2 + w;                  // 40 tiles: 4 b-tiles x 10 col-tiles
        int bt = tau / 10, ct = tau % 10;
        const char* Ay = h1b[p];              // h1(s-2) parity
        const unsigned long long* arow =
            (const unsigned long long*)(Ay + (size_t)(bt * 16 + l15) * 2048);
        const unsigned short* brow = woutb + (size_t)(ct * 16 + l15) * 1024;
        floatx4 accy = (floatx4){0.f, 0.f, 0.f, 0.f};
        #pragma unroll
        for (int ks = 0; ks < 32; ++ks) {
          int kg = ks * 32 + l4 * 8;
          union { unsigned long long uu[2]; bhalf8 v; } av;
          av.uu[0] = cload(arow + (kg >> 2));
          av.uu[1] = cload(arow + (kg >> 2) + 1);
          bhalf8 bb = *(const bhalf8*)(brow + kg);
          accy = __builtin_amdgcn_mfma_f32_16x16x32_bf16(av.v, bb, accy, 0, 0, 0);
        }
        int col = ct * 16 + l15;
        float bo = bout[col];
        int t2 = s - 2;
        #pragma unroll
        for (int i = 0; i < 4; ++i) {
          int b = bt * 16 + l4 * 4 + i;
          out[(size_t)b * 80000 + (size_t)(col >> 1) * 1000 + t2 * 2 + (col & 1)] = accy[i] + bo;
        }
      }
      __syncthreads();   // drain y before polling / next slot's counted vmcnt
      if (tid == 0 && !dead) {
        int it = 0;
        while (__hip_atomic_load(&rel[s], __ATOMIC_RELAXED, __HIP_MEMORY_SCOPE_AGENT) == 0) {
          __builtin_amdgcn_s_sleep(2);
          if (++it > 1000000) { dead = 1; break; }  // bounded failsafe: no hang
        }
      }
      __syncthreads();
    } else {
      // final slot: only y(s-2) remains
      if (layer == 0 && c < 20 && w < 2) {
        int tau = c * 2 + w;
        int bt = tau / 10, ct = tau % 10;
        const char* Ay = h1b[p];
        const unsigned long long* arow =
            (const unsigned long long*)(Ay + (size_t)(bt * 16 + l15) * 2048);
        const unsigned short* brow = woutb + (size_t)(ct * 16 + l15) * 1024;
        floatx4 accy = (floatx4){0.f, 0.f, 0.f, 0.f};
        #pragma unroll
        for (int ks = 0; ks < 32; ++ks) {
          int kg = ks * 32 + l4 * 8;
          union { unsigned long long uu[2]; bhalf8 v; } av;
          av.uu[0] = cload(arow + (kg >> 2));
          av.uu[1] = cload(arow + (kg >> 2) + 1);
          bhalf8 bb = *(const bhalf8*)(brow + kg);
          accy = __builtin_amdgcn_mfma_f32_16x16x32_bf16(av.v, bb, accy, 0, 0, 0);
        }
        int col = ct * 16 + l15;
        float bo = bout[col];
        int t2 = s - 2;
        #pragma unroll
        for (int i = 0; i < 4; ++i) {
          int b = bt * 16 + l4 * 4 + i;
          out[(size_t)b * 80000 + (size_t)(col >> 1) * 1000 + t2 * 2 + (col & 1)] = accy[i] + bo;
        }
      }
    }
  }
}

extern "C" void kernel_launch(void* const* d_in, const int* in_sizes, int n_in,
                              void* d_out, int out_size, void* d_ws, size_t ws_size,
                              hipStream_t stream) {
  const float* res  = (const float*)d_in[0];
  const float* Wih  = (const float*)d_in[1];
  const float* Whh  = (const float*)d_in[2];
  const float* bih  = (const float*)d_in[3];
  const float* bhh  = (const float*)d_in[4];
  const float* Wout = (const float*)d_in[5];
  const float* bout = (const float*)d_in[6];
  float* out = (float*)d_out;
  char* ws = (char*)d_ws;
  if (ws_size < 91557888u) return;  // workspace too small; fail loudly via wrong output

  unsigned short* woutb = (unsigned short*)(ws + 528384);
  unsigned short* wihb  = (unsigned short*)(ws + 856064);
  unsigned short* whhb  = (unsigned short*)(ws + 13438976);
  unsigned short* xb    = (unsigned short*)(ws + 26021888);

  // zero arrival counters + release flags + bf16 h state (both parities)
  hipMemsetAsync(ws, 0, 528384, stream);
  prep_w<<<4096, 256, 0, stream>>>(Wih, Whh, Wout, wihb, whhb, woutb);
  prep_x<<<dim3(16, 32, 64), dim3(32, 8), 0, stream>>>(res, xb);
  gru_main<<<NWG, BLOCK, 0, stream>>>(xb, wihb, whhb, woutb, bih, bhh, bout, ws, out);
}